// Round 2
// baseline (4933.160 us; speedup 1.0000x reference)
//
#include <hip/hip_runtime.h>
#include <math.h>

// Problem constants
#define Bb 16
#define Cc 512
#define Nn 4096
// derived (all element counts, fp32)
#define QKV_BSTRIDE (1536L * 4096)   // per-batch stride of qkv region (3 x C x N)
#define MQK_BSTRIDE (1024L * 4096)   // per-batch stride of mqk region (2 x C x N)
#define CN_STRIDE   (512L * 4096)    // C x N = 2^21

#define TM 64
#define TN 64
#define TK 16

// ---------------------------------------------------------------------------
// Tiled fp32 GEMM, C[M x N] = A[M x K] @ B[K x N] (+bias) (+accum into C)
// A row-major with leading dim lda; B row-major ld = N; C row-major ld = N.
// Grid: (N/64, M/64, batch). Per-batch strides sA/sB/sC (0 for shared).
// 256 threads, 4x4 micro-tile per thread.
// ---------------------------------------------------------------------------
__global__ __launch_bounds__(256) void gemm_nn(
    const float* __restrict__ A, int lda,
    const float* __restrict__ B,
    const float* __restrict__ bias,
    float* __restrict__ C,
    int K, int N,
    long sA, long sB, long sC,
    int add_bias, int accum)
{
    __shared__ float As[TK][TM];   // As[k][m]
    __shared__ float Bs[TK][TN];   // Bs[k][n]

    const int t = threadIdx.x;
    const int m0 = blockIdx.y * TM;
    const int n0 = blockIdx.x * TN;
    A += (long)blockIdx.z * sA;
    B += (long)blockIdx.z * sB;
    C += (long)blockIdx.z * sC;

    const int ar = t >> 2;          // 0..63 (A tile row)
    const int ac = (t & 3) << 2;    // 0,4,8,12 (A tile col, float4)
    const int br = t >> 4;          // 0..15 (B tile row)
    const int bc = (t & 15) << 2;   // 0..60 (B tile col, float4)

    const int tx = t & 15;          // output col group
    const int ty = t >> 4;          // output row group

    float acc[4][4] = {};

    for (int k0 = 0; k0 < K; k0 += TK) {
        float4 av = *(const float4*)&A[(long)(m0 + ar) * lda + (k0 + ac)];
        float4 bv = *(const float4*)&B[(long)(k0 + br) * N + (n0 + bc)];
        As[ac + 0][ar] = av.x;
        As[ac + 1][ar] = av.y;
        As[ac + 2][ar] = av.z;
        As[ac + 3][ar] = av.w;
        *(float4*)&Bs[br][bc] = bv;
        __syncthreads();
#pragma unroll
        for (int kk = 0; kk < TK; ++kk) {
            float4 a4 = *(const float4*)&As[kk][ty * 4];
            float4 b4 = *(const float4*)&Bs[kk][tx * 4];
            float a[4] = {a4.x, a4.y, a4.z, a4.w};
            float b[4] = {b4.x, b4.y, b4.z, b4.w};
#pragma unroll
            for (int i = 0; i < 4; ++i)
#pragma unroll
                for (int j = 0; j < 4; ++j)
                    acc[i][j] = fmaf(a[i], b[j], acc[i][j]);
        }
        __syncthreads();
    }

#pragma unroll
    for (int i = 0; i < 4; ++i) {
        int m = m0 + ty * 4 + i;
        float bv = add_bias ? bias[m] : 0.0f;
        long idx = (long)m * N + (n0 + tx * 4);
        float4 o;
        o.x = acc[i][0] + bv;
        o.y = acc[i][1] + bv;
        o.z = acc[i][2] + bv;
        o.w = acc[i][3] + bv;
        if (accum) {
            float4 old = *(const float4*)&C[idx];
            o.x += old.x; o.y += old.y; o.z += old.z; o.w += old.w;
        }
        *(float4*)&C[idx] = o;
    }
}

// ---------------------------------------------------------------------------
// Tiled fp32 GEMM NT: C[M x Nc] = scale * (A[M x K] @ B[Nc x K]^T)
// A ld = K, B ld = K, C ld = Nc. Grid: (Nc/64, M/64, batch).
// ---------------------------------------------------------------------------
__global__ __launch_bounds__(256) void gemm_nt(
    const float* __restrict__ A,
    const float* __restrict__ B,
    float* __restrict__ C,
    int K, int Nc,
    long sA, long sB, long sC, float scale)
{
    __shared__ float As[TK][TM];
    __shared__ float Bs[TK][TN];

    const int t = threadIdx.x;
    const int m0 = blockIdx.y * TM;
    const int n0 = blockIdx.x * TN;
    A += (long)blockIdx.z * sA;
    B += (long)blockIdx.z * sB;
    C += (long)blockIdx.z * sC;

    const int ar = t >> 2;
    const int ac = (t & 3) << 2;
    const int tx = t & 15;
    const int ty = t >> 4;

    float acc[4][4] = {};

    for (int k0 = 0; k0 < K; k0 += TK) {
        float4 av = *(const float4*)&A[(long)(m0 + ar) * K + (k0 + ac)];
        float4 bv = *(const float4*)&B[(long)(n0 + ar) * K + (k0 + ac)];
        As[ac + 0][ar] = av.x;
        As[ac + 1][ar] = av.y;
        As[ac + 2][ar] = av.z;
        As[ac + 3][ar] = av.w;
        Bs[ac + 0][ar] = bv.x;
        Bs[ac + 1][ar] = bv.y;
        Bs[ac + 2][ar] = bv.z;
        Bs[ac + 3][ar] = bv.w;
        __syncthreads();
#pragma unroll
        for (int kk = 0; kk < TK; ++kk) {
            float4 a4 = *(const float4*)&As[kk][ty * 4];
            float4 b4 = *(const float4*)&Bs[kk][tx * 4];
            float a[4] = {a4.x, a4.y, a4.z, a4.w};
            float b[4] = {b4.x, b4.y, b4.z, b4.w};
#pragma unroll
            for (int i = 0; i < 4; ++i)
#pragma unroll
                for (int j = 0; j < 4; ++j)
                    acc[i][j] = fmaf(a[i], b[j], acc[i][j]);
        }
        __syncthreads();
    }

#pragma unroll
    for (int i = 0; i < 4; ++i) {
        int m = m0 + ty * 4 + i;
        long idx = (long)m * Nc + (n0 + tx * 4);
        float4 o;
        o.x = acc[i][0] * scale;
        o.y = acc[i][1] * scale;
        o.z = acc[i][2] * scale;
        o.w = acc[i][3] * scale;
        *(float4*)&C[idx] = o;
    }
}

// ---------------------------------------------------------------------------
// _q = softmax(-relu(q * mq), axis=n) done in place on the q rows of qkv.
// One block per (b, c) row of length 4096; 256 threads x 16 elems.
// Grid: G * 512 blocks (b is group-local).
// ---------------------------------------------------------------------------
__global__ __launch_bounds__(256) void q_softmax_kernel(
    float* __restrict__ qkv, const float* __restrict__ mqk)
{
    int row = blockIdx.x;
    int b = row >> 9;
    int c = row & 511;
    float* q = qkv + (long)b * QKV_BSTRIDE + (long)c * Nn;
    const float* mq = mqk + (long)b * MQK_BSTRIDE + (long)c * Nn;

    const int t = threadIdx.x;
    const int lane = t & 63;
    const int wave = t >> 6;
    __shared__ float red[8];

    float vals[16];
    float mx = -1e30f;
#pragma unroll
    for (int i = 0; i < 16; ++i) {
        int n = t + i * 256;
        float v = q[n] * mq[n];
        v = (v > 0.0f) ? -v : 0.0f;   // -relu
        vals[i] = v;
        mx = fmaxf(mx, v);
    }
#pragma unroll
    for (int off = 32; off > 0; off >>= 1) mx = fmaxf(mx, __shfl_xor(mx, off));
    if (lane == 0) red[wave] = mx;
    __syncthreads();
    mx = fmaxf(fmaxf(red[0], red[1]), fmaxf(red[2], red[3]));

    float sum = 0.0f;
#pragma unroll
    for (int i = 0; i < 16; ++i) {
        vals[i] = __expf(vals[i] - mx);
        sum += vals[i];
    }
#pragma unroll
    for (int off = 32; off > 0; off >>= 1) sum += __shfl_xor(sum, off);
    if (lane == 0) red[4 + wave] = sum;
    __syncthreads();
    sum = red[4] + red[5] + red[6] + red[7];
    float inv = 1.0f / sum;
#pragma unroll
    for (int i = 0; i < 16; ++i) q[t + i * 256] = vals[i] * inv;
}

// ---------------------------------------------------------------------------
// _k = relu(k * mk) in place on the k rows of qkv. float4 elementwise.
// Flat index i over G * 512 * 4096 elements (the logical k tensor).
// ---------------------------------------------------------------------------
__global__ __launch_bounds__(256) void k_relu_kernel(
    float* __restrict__ qkv, const float* __restrict__ mqk)
{
    long i = ((long)blockIdx.x * 256 + threadIdx.x) * 4;
    long b = i >> 21;                    // / (512*4096)
    long rem = i & ((1L << 21) - 1);
    float* kp = qkv + b * QKV_BSTRIDE + CN_STRIDE + rem;
    const float* mp = mqk + b * MQK_BSTRIDE + CN_STRIDE + rem;
    float4 kv = *(const float4*)kp;
    float4 mv = *(const float4*)mp;
    float4 o;
    o.x = fmaxf(kv.x * mv.x, 0.0f);
    o.y = fmaxf(kv.y * mv.y, 0.0f);
    o.z = fmaxf(kv.z * mv.z, 0.0f);
    o.w = fmaxf(kv.w * mv.w, 0.0f);
    *(float4*)kp = o;
}

// ---------------------------------------------------------------------------
// Row softmax over attn scores, rows of length 512, in place.
// One block per row; 256 threads x 2 elems.
// ---------------------------------------------------------------------------
__global__ __launch_bounds__(256) void attn_softmax_kernel(float* __restrict__ attn)
{
    float* p = attn + (long)blockIdx.x * 512;
    const int t = threadIdx.x;
    const int lane = t & 63;
    const int wave = t >> 6;
    __shared__ float red[8];

    float v0 = p[t], v1 = p[t + 256];
    float mx = fmaxf(v0, v1);
#pragma unroll
    for (int off = 32; off > 0; off >>= 1) mx = fmaxf(mx, __shfl_xor(mx, off));
    if (lane == 0) red[wave] = mx;
    __syncthreads();
    mx = fmaxf(fmaxf(red[0], red[1]), fmaxf(red[2], red[3]));

    float e0 = __expf(v0 - mx);
    float e1 = __expf(v1 - mx);
    float sum = e0 + e1;
#pragma unroll
    for (int off = 32; off > 0; off >>= 1) sum += __shfl_xor(sum, off);
    if (lane == 0) red[4 + wave] = sum;
    __syncthreads();
    sum = red[4] + red[5] + red[6] + red[7];
    float inv = 1.0f / sum;
    p[t] = e0 * inv;
    p[t + 256] = e1 * inv;
}

// ---------------------------------------------------------------------------
// out = sigmoid(glin) * r + (1 - sigmoid(glin)) * y, flat G*512*4096.
// ---------------------------------------------------------------------------
__global__ __launch_bounds__(256) void final_kernel(
    const float* __restrict__ glin, const float* __restrict__ r,
    const float* __restrict__ y, float* __restrict__ out)
{
    long i = ((long)blockIdx.x * 256 + threadIdx.x) * 4;
    float4 gl = *(const float4*)&glin[i];
    float4 rv = *(const float4*)&r[i];
    float4 yv = *(const float4*)&y[i];
    float4 o;
    float g;
    g = 1.0f / (1.0f + __expf(-gl.x)); o.x = g * rv.x + (1.0f - g) * yv.x;
    g = 1.0f / (1.0f + __expf(-gl.y)); o.y = g * rv.y + (1.0f - g) * yv.y;
    g = 1.0f / (1.0f + __expf(-gl.z)); o.z = g * rv.z + (1.0f - g) * yv.z;
    g = 1.0f / (1.0f + __expf(-gl.w)); o.w = g * rv.w + (1.0f - g) * yv.w;
    *(float4*)&out[i] = o;
}

// ---------------------------------------------------------------------------
// Launch. Workspace footprint per batch: (3 + 2) * C * N * 4 B = 40 MiB.
// Process batches in the largest group G (divisor of 16) that fits ws_size.
// G is a pure function of the constant ws_size -> identical work every call
// (graph-capture safe).
// ---------------------------------------------------------------------------
extern "C" void kernel_launch(void* const* d_in, const int* in_sizes, int n_in,
                              void* d_out, int out_size, void* d_ws, size_t ws_size,
                              hipStream_t stream)
{
    const float* x    = (const float*)d_in[0];   // 16*512*4096
    const float* Wqkv = (const float*)d_in[1];   // 1536*512
    const float* bqkv = (const float*)d_in[2];
    const float* Wm   = (const float*)d_in[3];   // 1024*512
    const float* bm   = (const float*)d_in[4];
    const float* Wg   = (const float*)d_in[5];   // 512*1024
    const float* bg   = (const float*)d_in[6];
    const float* Wr   = (const float*)d_in[7];   // 512*512
    const float* br   = (const float*)d_in[8];

    float* out      = (float*)d_out;                   // 16*512*4096
    float* attn_all = out + (long)Bb * Cc * Nn;        // 16*512*512

    const size_t per_batch_bytes = (size_t)(QKV_BSTRIDE + MQK_BSTRIDE) * sizeof(float); // 40 MiB
    int G = 16;
    while (G > 1 && (size_t)G * per_batch_bytes > ws_size) G >>= 1;

    dim3 blk(256);
    const float inv_sqrt_c = 0.044194173824159216f;     // 1/sqrt(512)

    for (int b0 = 0; b0 < Bb; b0 += G) {
        const float* xg    = x + (long)b0 * CN_STRIDE;
        float*       outg  = out + (long)b0 * CN_STRIDE;
        float*       attng = attn_all + (long)b0 * Cc * Cc;

        // Group-local workspace layout:
        //   qkv : [G][1536][4096]  (later reused for r)
        //   mqk : [G][1024][4096]  (later reused for y + glin)
        float* qkv  = (float*)d_ws;
        float* mqk  = qkv + (long)G * QKV_BSTRIDE;
        float* y    = mqk;                              // first half of mqk region
        float* glin = mqk + (long)G * CN_STRIDE;        // second half of mqk region
        float* r    = qkv;                              // reuse after v dead

        // 1. qkv = Wqkv @ x + bqkv
        gemm_nn<<<dim3(Nn / TN, 1536 / TM, G), blk, 0, stream>>>(
            Wqkv, 512, xg, bqkv, qkv, 512, Nn, 0L, CN_STRIDE, QKV_BSTRIDE, 1, 0);

        // 2. mqk = Wm @ v + bm   (v = qkv rows [1024,1536))
        gemm_nn<<<dim3(Nn / TN, 1024 / TM, G), blk, 0, stream>>>(
            Wm, 512, qkv + 2L * CN_STRIDE, bm, mqk, 512, Nn, 0L, QKV_BSTRIDE, MQK_BSTRIDE, 1, 0);

        // 3. _q = softmax(-relu(q*mq)) in place
        q_softmax_kernel<<<G * Cc, blk, 0, stream>>>(qkv, mqk);

        // 4. _k = relu(k*mk) in place
        k_relu_kernel<<<(G * (int)(CN_STRIDE / 4 / 256)), blk, 0, stream>>>(qkv, mqk);

        // 5. scores = (_q @ _k^T) / sqrt(C) -> attn region of d_out
        gemm_nt<<<dim3(Cc / TN, Cc / TM, G), blk, 0, stream>>>(
            qkv, qkv + CN_STRIDE, attng, Nn, Cc,
            QKV_BSTRIDE, QKV_BSTRIDE, (long)Cc * Cc, inv_sqrt_c);

        // 6. attn = softmax(scores) in place
        attn_softmax_kernel<<<G * Cc, blk, 0, stream>>>(attng);

        // 7. y = attn @ v   (into first half of mqk region)
        gemm_nn<<<dim3(Nn / TN, Cc / TM, G), blk, 0, stream>>>(
            attng, 512, qkv + 2L * CN_STRIDE, nullptr, y, 512, Nn,
            (long)Cc * Cc, QKV_BSTRIDE, CN_STRIDE, 0, 0);

        // 8a. glin = Wg[:, :512] @ y + bg
        gemm_nn<<<dim3(Nn / TN, Cc / TM, G), blk, 0, stream>>>(
            Wg, 1024, y, bg, glin, 512, Nn, 0L, CN_STRIDE, CN_STRIDE, 1, 0);

        // 8b. glin += Wg[:, 512:] @ x
        gemm_nn<<<dim3(Nn / TN, Cc / TM, G), blk, 0, stream>>>(
            Wg + 512, 1024, xg, nullptr, glin, 512, Nn, 0L, CN_STRIDE, CN_STRIDE, 0, 1);

        // 9. r = Wr @ x + br   (into qkv region, q/k/v dead)
        gemm_nn<<<dim3(Nn / TN, Cc / TM, G), blk, 0, stream>>>(
            Wr, 512, xg, br, r, 512, Nn, 0L, CN_STRIDE, CN_STRIDE, 1, 0);

        // 10. out = g*r + (1-g)*y
        final_kernel<<<(G * (int)(CN_STRIDE / 4 / 256)), blk, 0, stream>>>(glin, r, y, outg);
    }
}

// Round 3
// 1269.073 us; speedup vs baseline: 3.8872x; 3.8872x over previous
//
#include <hip/hip_runtime.h>
#include <math.h>

// Problem constants
#define Bb 16
#define Cc 512
#define Nn 4096
#define CN (512L * 4096)           // elements of one [C][N] or [N][C] plane

typedef __bf16 bf16x8 __attribute__((ext_vector_type(8)));
typedef float  floatx4 __attribute__((ext_vector_type(4)));

__device__ __forceinline__ unsigned short f2bf(float f) {
    unsigned int u = __float_as_uint(f);
    unsigned int r = (u + 0x7FFFu + ((u >> 16) & 1u)) >> 16;
    return (unsigned short)r;
}
__device__ __forceinline__ float bf2f(unsigned short s) {
    return __uint_as_float(((unsigned int)s) << 16);
}

// async 16B global->LDS (dest = wave-uniform base + lane*16)
__device__ __forceinline__ void gload16(const void* g, void* l) {
    __builtin_amdgcn_global_load_lds(
        (const __attribute__((address_space(1))) unsigned int*)g,
        (__attribute__((address_space(3))) unsigned int*)l,
        16, 0, 0);
}

// ---------------------------------------------------------------------------
// NT bf16 MFMA GEMM: C[M x N] = scale * (A[M x K] @ B[N x K]^T) + bias[col]
// A rows K-contiguous (pitch lda), B rows K-contiguous (pitch ldb).
// 128x128 tile, BK=32, 256 threads = 4 waves (2x2 of 64x64).
// LDS layout == fragment order: subtile s (16 rows), slot lane*16B holds
// A[s*16 + (lane&15)][(lane>>4)*8 .. +7]  -> ds_read_b128 conflict-free.
// OUTF32: write float, else bf16. SPLIT: A switches source at k=asplit.
// ---------------------------------------------------------------------------
template<int OUTF32, int SPLIT>
__global__ __launch_bounds__(256) void gemm_bt(
    const unsigned short* __restrict__ A1,
    const unsigned short* __restrict__ A2, int lda, int asplit,
    const unsigned short* __restrict__ B, int ldb,
    const float* __restrict__ bias,
    void* __restrict__ Cv, int ldc,
    int K, float scale,
    long sA, long sB, long sC)
{
    __shared__ __align__(16) unsigned short Alds[8 * 512];
    __shared__ __align__(16) unsigned short Blds[8 * 512];

    const int t    = threadIdx.x;
    const int lane = t & 63;
    const int wave = t >> 6;
    const int m0 = blockIdx.y * 128;
    const int n0 = blockIdx.x * 128;
    const int wm = (wave >> 1) * 64;
    const int wn = (wave & 1) * 64;

    const unsigned short* Ab1 = A1 + (size_t)blockIdx.z * sA;
    const unsigned short* Ab2 = SPLIT ? (A2 + (size_t)blockIdx.z * sA) : nullptr;
    const unsigned short* Bb_ = B + (size_t)blockIdx.z * sB;

    const int srow = lane & 15;         // row within 16-row subtile
    const int sk   = (lane >> 4) * 8;   // k-offset of this lane's 8 elems

    floatx4 acc[4][4] = {};

    for (int k0 = 0; k0 < K; k0 += 32) {
        const unsigned short* Asrc;
        int kk;
        if (SPLIT && k0 >= asplit) { Asrc = Ab2; kk = k0 - asplit; }
        else                       { Asrc = Ab1; kk = k0; }
#pragma unroll
        for (int s = 0; s < 2; ++s) {
            int sub = wave * 2 + s;
            const unsigned short* ga = Asrc + (size_t)(m0 + sub * 16 + srow) * lda + kk + sk;
            const unsigned short* gb = Bb_  + (size_t)(n0 + sub * 16 + srow) * ldb + k0 + sk;
            gload16(ga, &Alds[sub * 512]);
            gload16(gb, &Blds[sub * 512]);
        }
        __syncthreads();

        bf16x8 af[4], bfr[4];
#pragma unroll
        for (int i = 0; i < 4; ++i) {
            af[i]  = *(const bf16x8*)&Alds[((wm >> 4) + i) * 512 + lane * 8];
            bfr[i] = *(const bf16x8*)&Blds[((wn >> 4) + i) * 512 + lane * 8];
        }
#pragma unroll
        for (int i = 0; i < 4; ++i)
#pragma unroll
            for (int j = 0; j < 4; ++j)
                acc[i][j] = __builtin_amdgcn_mfma_f32_16x16x32_bf16(af[i], bfr[j], acc[i][j], 0, 0, 0);
        __syncthreads();
    }

    // epilogue: C/D layout col = lane&15, row = (lane>>4)*4 + reg  [m89/m91]
    const int rbase = (lane >> 4) * 4;
    const int cofs  = lane & 15;
#pragma unroll
    for (int j = 0; j < 4; ++j) {
        int col = n0 + wn + j * 16 + cofs;
        float bv = bias ? bias[col] : 0.0f;
#pragma unroll
        for (int i = 0; i < 4; ++i) {
#pragma unroll
            for (int r = 0; r < 4; ++r) {
                int row = m0 + wm + i * 16 + rbase + r;
                float v = acc[i][j][r] * scale + bv;
                if (OUTF32) {
                    float* C = (float*)Cv + (size_t)blockIdx.z * sC;
                    C[(size_t)row * ldc + col] = v;
                } else {
                    unsigned short* C = (unsigned short*)Cv + (size_t)blockIdx.z * sC;
                    C[(size_t)row * ldc + col] = f2bf(v);
                }
            }
        }
    }
}

// ---------------------------------------------------------------------------
// fp32 -> bf16 weight cast (n multiple of 1024)
// ---------------------------------------------------------------------------
__global__ __launch_bounds__(256) void wcast(const float* __restrict__ w,
                                             unsigned short* __restrict__ o, int n)
{
    int i = (blockIdx.x * 256 + threadIdx.x) * 4;
    float4 v = *(const float4*)&w[i];
    ushort4 u;
    u.x = f2bf(v.x); u.y = f2bf(v.y); u.z = f2bf(v.z); u.w = f2bf(v.w);
    *(ushort4*)&o[i] = u;
}

// ---------------------------------------------------------------------------
// x [c][n] fp32 (pitch 4096) -> x' [n][c] bf16 (pitch 512). grid (64,8,G).
// ---------------------------------------------------------------------------
__global__ __launch_bounds__(256) void transpose_x(const float* __restrict__ x,
                                                   unsigned short* __restrict__ xp)
{
    __shared__ unsigned short tile[64][65];   // tile[n_loc][c_loc]
    const float* X = x + (size_t)blockIdx.z * CN;
    unsigned short* O = xp + (size_t)blockIdx.z * CN;
    int n0 = blockIdx.x * 64, c0 = blockIdx.y * 64;
    int tq = (threadIdx.x & 15) * 4, tr = threadIdx.x >> 4;
#pragma unroll
    for (int r = 0; r < 4; ++r) {
        int cl = tr + r * 16;
        float4 v = *(const float4*)&X[(size_t)(c0 + cl) * 4096 + n0 + tq];
        tile[tq + 0][cl] = f2bf(v.x);
        tile[tq + 1][cl] = f2bf(v.y);
        tile[tq + 2][cl] = f2bf(v.z);
        tile[tq + 3][cl] = f2bf(v.w);
    }
    __syncthreads();
#pragma unroll
    for (int r = 0; r < 4; ++r) {
        int nl = tr + r * 16;
        ushort4 o;
        o.x = tile[nl][tq + 0]; o.y = tile[nl][tq + 1];
        o.z = tile[nl][tq + 2]; o.w = tile[nl][tq + 3];
        *(ushort4*)&O[(size_t)(n0 + nl) * 512 + c0 + tq] = o;
    }
}

// ---------------------------------------------------------------------------
// q/k transform + transpose:
//   T[c][n] (bf16, pitch 4096) = neg ? -relu(q'*m') : relu(k'*m')
// sources: qkv' [n][1536] col offset coff; mqk' [n][1024] col offset coff.
// grid (64, 8, G).
// ---------------------------------------------------------------------------
__global__ __launch_bounds__(256) void qk_transform(
    const unsigned short* __restrict__ qkv, const unsigned short* __restrict__ mqk,
    unsigned short* __restrict__ T, int coff, int neg)
{
    __shared__ __align__(8) unsigned short tile[64][68];  // tile[n_loc][c_loc]
    const unsigned short* S1 = qkv + (size_t)blockIdx.z * (4096L * 1536) + coff;
    const unsigned short* S2 = mqk + (size_t)blockIdx.z * (4096L * 1024) + coff;
    unsigned short* O = T + (size_t)blockIdx.z * CN;
    int n0 = blockIdx.x * 64, c0 = blockIdx.y * 64;
    int tq = (threadIdx.x & 15) * 4, tr = threadIdx.x >> 4;
#pragma unroll
    for (int r = 0; r < 4; ++r) {
        int nl = tr + r * 16;
        ushort4 a = *(const ushort4*)&S1[(size_t)(n0 + nl) * 1536 + c0 + tq];
        ushort4 m = *(const ushort4*)&S2[(size_t)(n0 + nl) * 1024 + c0 + tq];
        float f0 = fmaxf(bf2f(a.x) * bf2f(m.x), 0.0f);
        float f1 = fmaxf(bf2f(a.y) * bf2f(m.y), 0.0f);
        float f2 = fmaxf(bf2f(a.z) * bf2f(m.z), 0.0f);
        float f3 = fmaxf(bf2f(a.w) * bf2f(m.w), 0.0f);
        if (neg) { f0 = -f0; f1 = -f1; f2 = -f2; f3 = -f3; }
        ushort4 p;
        p.x = f2bf(f0); p.y = f2bf(f1); p.z = f2bf(f2); p.w = f2bf(f3);
        *(ushort4*)&tile[nl][tq] = p;
    }
    __syncthreads();
#pragma unroll
    for (int r = 0; r < 4; ++r) {
        int cl = tr + r * 16;
        ushort4 o;
        o.x = tile[tq + 0][cl]; o.y = tile[tq + 1][cl];
        o.z = tile[tq + 2][cl]; o.w = tile[tq + 3][cl];
        *(ushort4*)&O[(size_t)(c0 + cl) * 4096 + n0 + tq] = o;
    }
}

// ---------------------------------------------------------------------------
// Row softmax (len 4096) in place on bf16 rows. One block per row.
// ---------------------------------------------------------------------------
__global__ __launch_bounds__(256) void qsoftmax_bf(unsigned short* __restrict__ Q)
{
    unsigned short* p = Q + (size_t)blockIdx.x * 4096;
    const int t = threadIdx.x;
    const int lane = t & 63;
    const int wv = t >> 6;
    __shared__ float red[8];

    float vals[16];
    float mx = -1e30f;
#pragma unroll
    for (int i = 0; i < 16; ++i) {
        float v = bf2f(p[t + i * 256]);
        vals[i] = v;
        mx = fmaxf(mx, v);
    }
#pragma unroll
    for (int off = 32; off > 0; off >>= 1) mx = fmaxf(mx, __shfl_xor(mx, off));
    if (lane == 0) red[wv] = mx;
    __syncthreads();
    mx = fmaxf(fmaxf(red[0], red[1]), fmaxf(red[2], red[3]));

    float sum = 0.0f;
#pragma unroll
    for (int i = 0; i < 16; ++i) {
        vals[i] = __expf(vals[i] - mx);
        sum += vals[i];
    }
#pragma unroll
    for (int off = 32; off > 0; off >>= 1) sum += __shfl_xor(sum, off);
    if (lane == 0) red[4 + wv] = sum;
    __syncthreads();
    sum = red[4] + red[5] + red[6] + red[7];
    float inv = 1.0f / sum;
#pragma unroll
    for (int i = 0; i < 16; ++i) p[t + i * 256] = f2bf(vals[i] * inv);
}

// ---------------------------------------------------------------------------
// Row softmax (len 512) in place fp32 + bf16 copy. One block per row.
// ---------------------------------------------------------------------------
__global__ __launch_bounds__(256) void attn_softmax_dual(
    float* __restrict__ attnf, unsigned short* __restrict__ attnb)
{
    float* p = attnf + (size_t)blockIdx.x * 512;
    unsigned short* pb = attnb + (size_t)blockIdx.x * 512;
    const int t = threadIdx.x;
    const int lane = t & 63;
    const int wv = t >> 6;
    __shared__ float red[8];

    float v0 = p[t], v1 = p[t + 256];
    float mx = fmaxf(v0, v1);
#pragma unroll
    for (int off = 32; off > 0; off >>= 1) mx = fmaxf(mx, __shfl_xor(mx, off));
    if (lane == 0) red[wv] = mx;
    __syncthreads();
    mx = fmaxf(fmaxf(red[0], red[1]), fmaxf(red[2], red[3]));

    float e0 = __expf(v0 - mx);
    float e1 = __expf(v1 - mx);
    float sum = e0 + e1;
#pragma unroll
    for (int off = 32; off > 0; off >>= 1) sum += __shfl_xor(sum, off);
    if (lane == 0) red[4 + wv] = sum;
    __syncthreads();
    sum = red[4] + red[5] + red[6] + red[7];
    float inv = 1.0f / sum;
    float a0 = e0 * inv, a1 = e1 * inv;
    p[t] = a0;        p[t + 256] = a1;
    pb[t] = f2bf(a0); pb[t + 256] = f2bf(a1);
}

// ---------------------------------------------------------------------------
// final: out[c][n] fp32 = g*r + (1-g)*y from glin'/r'/y' [n][c] bf16 (pitch 512)
// with transpose via LDS. grid (64, 8, G).
// ---------------------------------------------------------------------------
__global__ __launch_bounds__(256) void final_fuse(
    const unsigned short* __restrict__ gl, const unsigned short* __restrict__ rr,
    const unsigned short* __restrict__ yy, float* __restrict__ out)
{
    __shared__ __align__(16) float tile[64][68];   // tile[n_loc][c_loc]
    size_t bo = (size_t)blockIdx.z * CN;
    const unsigned short* G_ = gl + bo;
    const unsigned short* R_ = rr + bo;
    const unsigned short* Y_ = yy + bo;
    float* O = out + bo;
    int n0 = blockIdx.x * 64, c0 = blockIdx.y * 64;
    int tq = (threadIdx.x & 15) * 4, tr = threadIdx.x >> 4;
#pragma unroll
    for (int r = 0; r < 4; ++r) {
        int nl = tr + r * 16;
        size_t base = (size_t)(n0 + nl) * 512 + c0 + tq;
        ushort4 g4 = *(const ushort4*)&G_[base];
        ushort4 r4 = *(const ushort4*)&R_[base];
        ushort4 y4 = *(const ushort4*)&Y_[base];
        float4 o;
        float g;
        g = 1.0f / (1.0f + __expf(-bf2f(g4.x))); o.x = g * bf2f(r4.x) + (1.0f - g) * bf2f(y4.x);
        g = 1.0f / (1.0f + __expf(-bf2f(g4.y))); o.y = g * bf2f(r4.y) + (1.0f - g) * bf2f(y4.y);
        g = 1.0f / (1.0f + __expf(-bf2f(g4.z))); o.z = g * bf2f(r4.z) + (1.0f - g) * bf2f(y4.z);
        g = 1.0f / (1.0f + __expf(-bf2f(g4.w))); o.w = g * bf2f(r4.w) + (1.0f - g) * bf2f(y4.w);
        *(float4*)&tile[nl][tq] = o;
    }
    __syncthreads();
#pragma unroll
    for (int r = 0; r < 4; ++r) {
        int cl = tr + r * 16;
        float4 o;
        o.x = tile[tq + 0][cl]; o.y = tile[tq + 1][cl];
        o.z = tile[tq + 2][cl]; o.w = tile[tq + 3][cl];
        *(float4*)&O[(size_t)(c0 + cl) * 4096 + n0 + tq] = o;
    }
}

// ---------------------------------------------------------------------------
// Launch. Per-batch bf16 workspace: 4096*(512+1536+1024+512+512) = 32 MiB.
// Fixed bf16 weights: 4 MiB. Adaptive group size G (pure fn of ws_size).
// ---------------------------------------------------------------------------
extern "C" void kernel_launch(void* const* d_in, const int* in_sizes, int n_in,
                              void* d_out, int out_size, void* d_ws, size_t ws_size,
                              hipStream_t stream)
{
    const float* x    = (const float*)d_in[0];
    const float* Wqkv = (const float*)d_in[1];
    const float* bqkv = (const float*)d_in[2];
    const float* Wm   = (const float*)d_in[3];
    const float* bm   = (const float*)d_in[4];
    const float* Wg   = (const float*)d_in[5];
    const float* bg   = (const float*)d_in[6];
    const float* Wr   = (const float*)d_in[7];
    const float* br   = (const float*)d_in[8];

    float* out      = (float*)d_out;
    float* attn_all = out + (size_t)Bb * CN;

    unsigned short* wq_bf = (unsigned short*)d_ws;
    unsigned short* wm_bf = wq_bf + 1536 * 512;
    unsigned short* wg_bf = wm_bf + 1024 * 512;
    unsigned short* wr_bf = wg_bf + 512 * 1024;
    unsigned short* dyn   = wr_bf + 512 * 512;
    const size_t fixed_bytes = (size_t)(1536 * 512 + 1024 * 512 + 512 * 1024 + 512 * 512) * 2;
    const size_t per_batch_bytes = (size_t)4096 * 4096 * 2;   // 32 MiB

    int G = 16;
    while (G > 1 && fixed_bytes + (size_t)G * per_batch_bytes > ws_size) G >>= 1;

    dim3 blk(256);
    const float inv_sqrt_c = 0.044194173824159216f;

    wcast<<<1536 * 512 / 1024, blk, 0, stream>>>(Wqkv, wq_bf, 1536 * 512);
    wcast<<<1024 * 512 / 1024, blk, 0, stream>>>(Wm,   wm_bf, 1024 * 512);
    wcast<<<512 * 1024 / 1024, blk, 0, stream>>>(Wg,   wg_bf, 512 * 1024);
    wcast<<<512 * 512  / 1024, blk, 0, stream>>>(Wr,   wr_bf, 512 * 512);

    for (int b0 = 0; b0 < Bb; b0 += G) {
        unsigned short* xp   = dyn;
        unsigned short* qkvp = xp   + (size_t)G * 4096 * 512;
        unsigned short* mqkp = qkvp + (size_t)G * 4096 * 1536;
        unsigned short* qp   = mqkp + (size_t)G * 4096 * 1024;
        unsigned short* kp   = qp   + (size_t)G * CN;
        unsigned short* yp   = mqkp;                         // alias (mqk dead)
        unsigned short* glp  = mqkp + (size_t)G * CN;        // alias
        unsigned short* rp   = qp;                           // alias (_q dead)
        unsigned short* abf  = kp;                           // alias (_k dead)

        const float* xg   = x + (size_t)b0 * CN;
        float* outg       = out + (size_t)b0 * CN;
        float* attng      = attn_all + (size_t)b0 * 512 * 512;

        // x' [n][c] bf16
        transpose_x<<<dim3(64, 8, G), blk, 0, stream>>>(xg, xp);

        // qkv' = x' @ Wqkv^T + bqkv
        gemm_bt<0, 0><<<dim3(12, 32, G), blk, 0, stream>>>(
            xp, nullptr, 512, 0, wq_bf, 512, bqkv, qkvp, 1536,
            512, 1.0f, 4096L * 512, 0L, 4096L * 1536);

        // mqk' = v' @ Wm^T + bm   (v' = qkv' cols [1024,1536))
        gemm_bt<0, 0><<<dim3(8, 32, G), blk, 0, stream>>>(
            qkvp + 1024, nullptr, 1536, 0, wm_bf, 512, bm, mqkp, 1024,
            512, 1.0f, 4096L * 1536, 0L, 4096L * 1024);

        // _q0[c][n] = -relu(q*mq)^T ; _k[c][n] = relu(k*mk)^T
        qk_transform<<<dim3(64, 8, G), blk, 0, stream>>>(qkvp, mqkp, qp, 0, 1);
        qk_transform<<<dim3(64, 8, G), blk, 0, stream>>>(qkvp, mqkp, kp, 512, 0);

        // _q = softmax over n
        qsoftmax_bf<<<G * 512, blk, 0, stream>>>(qp);

        // scores = (_q @ _k^T)/sqrt(C) -> fp32 attn region
        gemm_bt<1, 0><<<dim3(4, 4, G), blk, 0, stream>>>(
            qp, nullptr, 4096, 0, kp, 4096, nullptr, attng, 512,
            4096, inv_sqrt_c, CN, CN, 512L * 512);

        // attn = softmax(scores): fp32 in place + bf16 copy
        attn_softmax_dual<<<G * 512, blk, 0, stream>>>(attng, abf);

        // y' = v' @ attn^T
        gemm_bt<0, 0><<<dim3(4, 32, G), blk, 0, stream>>>(
            qkvp + 1024, nullptr, 1536, 0, abf, 512, nullptr, yp, 512,
            512, 1.0f, 4096L * 1536, 512L * 512, 4096L * 512);

        // glin' = [y'; x'] @ Wg^T + bg  (A switches at k=512)
        gemm_bt<0, 1><<<dim3(4, 32, G), blk, 0, stream>>>(
            yp, xp, 512, 512, wg_bf, 1024, bg, glp, 512,
            1024, 1.0f, 4096L * 512, 0L, 4096L * 512);

        // r' = x' @ Wr^T + br
        gemm_bt<0, 0><<<dim3(4, 32, G), blk, 0, stream>>>(
            xp, nullptr, 512, 0, wr_bf, 512, br, rp, 512,
            512, 1.0f, 4096L * 512, 0L, 4096L * 512);

        // out[c][n] = g*r + (1-g)*y (transposing)
        final_fuse<<<dim3(64, 8, G), blk, 0, stream>>>(glp, rp, yp, outg);
    }
}